// Round 1
// baseline (404.727 us; speedup 1.0000x reference)
//
#include <hip/hip_runtime.h>
#include <math.h>

// Problem constants (match reference setup_inputs)
constexpr int kB  = 8;
constexpr int kA  = 100000;
constexpr int kM  = 100;
constexpr int kCH = 85;     // 5 + NCLS
constexpr float kEPS = 1e-4f;

// log(EPS), log(1-EPS) in fp32
#define L0 (-9.210340371976182f)
#define L1 (-1.0000500033334732e-4f)

__device__ __forceinline__ float wave_reduce_f(float v) {
#pragma unroll
    for (int off = 32; off > 0; off >>= 1) v += __shfl_down(v, off, 64);
    return v;
}
__device__ __forceinline__ int wave_reduce_i(int v) {
#pragma unroll
    for (int off = 32; off > 0; off >>= 1) v += __shfl_down(v, off, 64);
    return v;
}

// ws layout: float ws_f[2*kB] = {cls_sum, box_sum} per batch,
//            int   ws_i[2*kB] = {n_cls, n_box} per batch (after the floats)
__global__ __launch_bounds__(256) void loss_main(
    const float* __restrict__ dt, const float* __restrict__ gt,
    const float* __restrict__ anchors, const int* __restrict__ assign,
    float* __restrict__ ws_f, int* __restrict__ ws_i)
{
    const int b = blockIdx.y;
    const int a = blockIdx.x * blockDim.x + threadIdx.x;

    float cls_c = 0.f, box_c = 0.f;
    int ncls_c = 0, nbox_c = 0;

    if (a < kA) {
        const int as = assign[b * kA + a];
        if (as >= 0) {                       // pos_cls
            const float* dp = dt + (size_t)b * kCH * kA + a;
            // P = sum of clipped predictions over channels 4..84
            float P = 0.f;
#pragma unroll 9
            for (int c = 4; c < kCH; ++c) {
                float x = dp[(size_t)c * kA];
                x = fminf(fmaxf(x, kEPS), 1.0f - kEPS);
                P += x;
            }
            float per = (L1 - L0) * P - 81.0f * L1;
            if (as >= 1) {                   // pos_box
                const int idx = min(as - 1, kM - 1);
                const float* g = gt + ((size_t)b * kM + idx) * 5;
                const float g0 = g[0], g1 = g[1], g2 = g[2], g3 = g[3];
                const int cls = (int)g[4];   // 1..NCLS
                float p_obj = fminf(fmaxf(dp[(size_t)4 * kA], kEPS), 1.0f - kEPS);
                float p_cls = fminf(fmaxf(dp[(size_t)(4 + cls) * kA], kEPS), 1.0f - kEPS);
                per += (2.0f * (p_obj + p_cls) - 2.0f) * (L0 - L1);

                const float4 av = ((const float4*)anchors)[a];
                const float aw = av.z - av.x, ah = av.w - av.y;
                const float ax = av.x + 0.5f * aw, ay = av.y + 0.5f * ah;
                const float gx = g0 + 0.5f * g2, gy = g1 + 0.5f * g3;
                const float d0 = (gx - ax) / aw - dp[0];
                const float d1 = (gy - ay) / ah - dp[(size_t)1 * kA];
                const float d2 = logf(g2 / aw) - dp[(size_t)2 * kA];
                const float d3 = logf(g3 / ah) - dp[(size_t)3 * kA];
                box_c = d0 * d0 + d1 * d1 + d2 * d2 + d3 * d3;
                nbox_c = 1;
            }
            cls_c = per;
            ncls_c = 1;
        }
    }

    // block reduction: wave shuffle -> LDS across 4 waves -> atomics
    __shared__ float s_cls[4], s_box[4];
    __shared__ int   s_nc[4], s_nb[4];
    cls_c  = wave_reduce_f(cls_c);
    box_c  = wave_reduce_f(box_c);
    ncls_c = wave_reduce_i(ncls_c);
    nbox_c = wave_reduce_i(nbox_c);
    const int lane = threadIdx.x & 63, wid = threadIdx.x >> 6;
    if (lane == 0) { s_cls[wid] = cls_c; s_box[wid] = box_c; s_nc[wid] = ncls_c; s_nb[wid] = nbox_c; }
    __syncthreads();
    if (threadIdx.x == 0) {
        float cs = 0.f, bs = 0.f; int nc = 0, nb = 0;
#pragma unroll
        for (int w = 0; w < 4; ++w) { cs += s_cls[w]; bs += s_box[w]; nc += s_nc[w]; nb += s_nb[w]; }
        atomicAdd(&ws_f[b * 2 + 0], cs);
        atomicAdd(&ws_f[b * 2 + 1], bs);
        atomicAdd(&ws_i[b * 2 + 0], nc);
        atomicAdd(&ws_i[b * 2 + 1], nb);
    }
}

__global__ void loss_final(const float* __restrict__ ws_f,
                           const int* __restrict__ ws_i,
                           float* __restrict__ out)
{
    if (threadIdx.x == 0 && blockIdx.x == 0) {
        float tot = 0.f;
#pragma unroll
        for (int b = 0; b < kB; ++b) {
            const float cls_sum = ws_f[b * 2 + 0];
            const float box_sum = ws_f[b * 2 + 1];
            const float n_cls = (float)ws_i[b * 2 + 0];
            const float n_box = (float)ws_i[b * 2 + 1];
            const float cls_loss = cls_sum / fmaxf(n_cls, 1.0f);
            const float box_loss = (n_box > 0.f) ? box_sum / fmaxf(n_box, 1.0f) : 0.f;
            tot += cls_loss + box_loss;
        }
        out[0] = tot / (float)kB;
    }
}

extern "C" void kernel_launch(void* const* d_in, const int* in_sizes, int n_in,
                              void* d_out, int out_size, void* d_ws, size_t ws_size,
                              hipStream_t stream) {
    const float* dt      = (const float*)d_in[0];   // [B, 85, A] fp32
    const float* gt      = (const float*)d_in[1];   // [B, M, 5] fp32
    const float* anchors = (const float*)d_in[2];   // [A, 4] fp32
    const int*   assign  = (const int*)d_in[3];     // [B, A] int32
    float* out = (float*)d_out;

    float* ws_f = (float*)d_ws;
    int*   ws_i = (int*)(ws_f + 2 * kB);

    // zero the accumulators (d_ws is poisoned 0xAA before every call)
    hipMemsetAsync(d_ws, 0, (2 * kB) * sizeof(float) + (2 * kB) * sizeof(int), stream);

    dim3 grid((kA + 255) / 256, kB);
    loss_main<<<grid, 256, 0, stream>>>(dt, gt, anchors, assign, ws_f, ws_i);
    loss_final<<<1, 64, 0, stream>>>(ws_f, ws_i, out);
}